// Round 3
// baseline (319.415 us; speedup 1.0000x reference)
//
#include <hip/hip_runtime.h>
#include <stdint.h>

#define M_TOK 32768
#define N_OUT 1024
#define K_IN  1024

#define BM 256
#define BN 256
#define BK 64

typedef __bf16 bf16_t;
typedef bf16_t bf16x8 __attribute__((ext_vector_type(8)));
typedef float  floatx4 __attribute__((ext_vector_type(4)));

__device__ __forceinline__ unsigned short f2bf(float f) {
    // round-to-nearest-even fp32 -> bf16
    uint32_t u = __float_as_uint(f);
    u += 0x7FFFu + ((u >> 16) & 1u);
    return (unsigned short)(u >> 16);
}

// x fp32 -> bf16, 8 elements per thread, grid-stride (G11: ~2048 blocks)
__global__ void cvt_x_kernel(const float* __restrict__ x, unsigned short* __restrict__ xb) {
    const size_t stride = (size_t)gridDim.x * blockDim.x;
    const size_t ngrp = (size_t)M_TOK * K_IN / 8;
    for (size_t i = (size_t)blockIdx.x * blockDim.x + threadIdx.x; i < ngrp; i += stride) {
        const float4* xv = (const float4*)(x + i * 8);
        float4 a = xv[0];
        float4 b = xv[1];
        unsigned int p0 = (unsigned int)f2bf(a.x) | ((unsigned int)f2bf(a.y) << 16);
        unsigned int p1 = (unsigned int)f2bf(a.z) | ((unsigned int)f2bf(a.w) << 16);
        unsigned int p2 = (unsigned int)f2bf(b.x) | ((unsigned int)f2bf(b.y) << 16);
        unsigned int p3 = (unsigned int)f2bf(b.z) | ((unsigned int)f2bf(b.w) << 16);
        uint4 o; o.x = p0; o.y = p1; o.z = p2; o.w = p3;
        *(uint4*)(xb + i * 8) = o;
    }
}

// sign(w) -> bf16 {+1,-1,0}, 4 elements per thread
__global__ void cvt_w_kernel(const float* __restrict__ w, unsigned short* __restrict__ wb) {
    size_t i = (size_t)blockIdx.x * blockDim.x + threadIdx.x;   // group of 4
    const float4* wv = (const float4*)(w + i * 4);
    float4 a = wv[0];
    unsigned short s0 = (a.x > 0.f) ? 0x3F80u : ((a.x < 0.f) ? 0xBF80u : 0u);
    unsigned short s1 = (a.y > 0.f) ? 0x3F80u : ((a.y < 0.f) ? 0xBF80u : 0u);
    unsigned short s2 = (a.z > 0.f) ? 0x3F80u : ((a.z < 0.f) ? 0xBF80u : 0u);
    unsigned short s3 = (a.w > 0.f) ? 0x3F80u : ((a.w < 0.f) ? 0xBF80u : 0u);
    uint2 o;
    o.x = (unsigned int)s0 | ((unsigned int)s1 << 16);
    o.y = (unsigned int)s2 | ((unsigned int)s3 << 16);
    *(uint2*)(wb + i * 4) = o;
}

// async 16B global -> LDS (direct, no VGPR round trip)
__device__ __forceinline__ void stage16(const unsigned short* g, unsigned short* l) {
    __builtin_amdgcn_global_load_lds(
        (const __attribute__((address_space(1))) unsigned int*)g,
        (__attribute__((address_space(3))) unsigned int*)l, 16, 0, 0);
}

// ---------------- 8-phase 256x256 template (T1+T2+T3+T4+T5) ----------------
// LDS: sA[2][2][128][64] bf16 (buf, half, row, granule-swizzled) + sB same.
// Swizzle: within a row (8 granules of 16 B), physical granule = logical ^ (row&7).
//   gload_lds writes linearly -> the SOURCE global address is pre-swizzled;
//   ds_read applies the same XOR -> fragment reads are 2-way (= free) on banks.
//
// Round-2 fix: burst staging for 4-phase vmcnt cover.
//   buf0's last read is ph3; buf1's last read is ph7.  So:
//     ph4: stage ALL of t0+2 -> buf0 (8 loads); gate vmcnt(8)
//          -> waits t1's 8 loads, issued at the PREVIOUS ph8 (4 phases ago)
//     ph8: stage ALL of t1+2 -> buf1 (8 loads); gate vmcnt(8)
//          -> waits t0+2's 8 loads, issued at ph4 (4 phases ago)
//   The youngest gated load always has ~4 phases (>2000 cyc) of cover vs
//   ~900 cyc HBM latency; vmcnt never drains to 0 in the loop.
// Safety: each stage issues strictly after the closing barrier of its
// buffer's last-read phase; each buffer is read only after a counted vmcnt
// covering all 8 of its loads plus a barrier.

#define PH_OPEN() do { asm volatile("" ::: "memory"); \
    __builtin_amdgcn_s_barrier(); \
    __builtin_amdgcn_s_setprio(1); } while(0)

#define PH_CLOSE() do { __builtin_amdgcn_s_setprio(0); \
    asm volatile("s_waitcnt lgkmcnt(0)" ::: "memory"); \
    __builtin_amdgcn_s_barrier(); } while(0)

#define PH_CLOSE_VM8() do { __builtin_amdgcn_s_setprio(0); \
    asm volatile("s_waitcnt vmcnt(8)" ::: "memory"); \
    asm volatile("s_waitcnt lgkmcnt(0)" ::: "memory"); \
    __builtin_amdgcn_s_barrier(); } while(0)

#define STAGE_A(p,h,kt) do { \
    const unsigned short* _g = gAs + (size_t)((h) * 128) * K_IN + (kt) * BK; \
    unsigned short* _l = lAs + (p) * 16384 + (h) * 8192; \
    stage16(_g, _l); \
    stage16(_g + (size_t)(64 * K_IN), _l + 4096); \
} while(0)

#define STAGE_B(p,h,kt) do { \
    const unsigned short* _g = gBs + (size_t)((h) * 128) * K_IN + (kt) * BK; \
    unsigned short* _l = lBs + (p) * 16384 + (h) * 8192; \
    stage16(_g, _l); \
    stage16(_g + (size_t)(64 * K_IN), _l + 4096); \
} while(0)

// stage one whole K-tile (A + B, 4 half-tiles, 8 gload_lds per thread)
#define STAGE_T(p,kt) do { \
    STAGE_A(p,0,kt); STAGE_A(p,1,kt); \
    STAGE_B(p,0,kt); STAGE_B(p,1,kt); \
} while(0)

#define LOAD_A(p,mh) do { _Pragma("unroll") \
    for (int mi = 0; mi < 4; ++mi) { \
        const unsigned short* _b = rA + (p) * 16384 + ((mh) * 64 + mi * 16) * 64; \
        af[mi][0] = *(const bf16x8*)(_b + gp0 * 8); \
        af[mi][1] = *(const bf16x8*)(_b + gp1 * 8); \
    } } while(0)

#define LOAD_B(p,nh) do { _Pragma("unroll") \
    for (int ni = 0; ni < 2; ++ni) { \
        const unsigned short* _b = rB + (p) * 16384 + ((nh) * 32 + ni * 16) * 64; \
        bf[(nh) * 2 + ni][0] = *(const bf16x8*)(_b + gp0 * 8); \
        bf[(nh) * 2 + ni][1] = *(const bf16x8*)(_b + gp1 * 8); \
    } } while(0)

#define MFMA_Q(mh,nh) do { _Pragma("unroll") \
    for (int mi = 0; mi < 4; ++mi) { _Pragma("unroll") \
        for (int ni = 0; ni < 2; ++ni) { \
            acc[(mh)*4+mi][(nh)*2+ni] = __builtin_amdgcn_mfma_f32_16x16x32_bf16( \
                af[mi][0], bf[(nh)*2+ni][0], acc[(mh)*4+mi][(nh)*2+ni], 0, 0, 0); \
            acc[(mh)*4+mi][(nh)*2+ni] = __builtin_amdgcn_mfma_f32_16x16x32_bf16( \
                af[mi][1], bf[(nh)*2+ni][1], acc[(mh)*4+mi][(nh)*2+ni], 0, 0, 0); \
        } } } while(0)

__global__ __launch_bounds__(512, 2) void gemm8p(
    const unsigned short* __restrict__ A,   // [M][K] bf16 bits
    const unsigned short* __restrict__ B,   // [N][K] bf16 bits (= sign(W))
    const float* __restrict__ bias,         // [N]
    float* __restrict__ C)                  // [M][N]
{
    extern __shared__ unsigned short lds[];     // 128 KiB
    unsigned short* sA = lds;                   // 32768 shorts (64 KB)
    unsigned short* sB = lds + 32768;

    const int t = threadIdx.x;
    const int b = blockIdx.x;
    // XCD swizzle: nwg=512 (%8==0): each XCD owns 64 consecutive wg = 16 bm x 4 bn
    const int wg = ((b & 7) << 6) + (b >> 3);
    const int bm = wg >> 2;       // 0..127
    const int bn = wg & 3;        // 0..3

    const int w    = t >> 6;      // 0..7
    const int lane = t & 63;
    const int wm   = w >> 2;      // 0..1  (A half / C row half)
    const int wn   = w & 3;       // 0..3  (C col quarter)
    const int lrow = lane & 15;
    const int quad = lane >> 4;

    // --- staging addressing: wave w covers rows h*128 + w*8 + lane/8 (+64),
    //     granule (lane&7); pre-swizzled global source granule = (lane&7)^(lane>>3)
    const int srow = (w << 3) + (lane >> 3);
    const int glog = (lane & 7) ^ (lane >> 3);
    const unsigned short* gAs = A + (size_t)(bm * BM + srow) * K_IN + glog * 8;
    const unsigned short* gBs = B + (size_t)(bn * BN + srow) * K_IN + glog * 8;
    unsigned short* lAs = sA + t * 8;   // linear dest
    unsigned short* lBs = sB + t * 8;

    // --- fragment read bases; read granule = (ks*4+quad) ^ (row&7), row&7==lrow&7
    const unsigned short* rA = sA + wm * 8192 + lrow * 64;
    const unsigned short* rB = sB + (wn >> 1) * 8192 + ((wn & 1) * 64 + lrow) * 64;
    const int gp0 = quad ^ (lrow & 7);        // ks=0
    const int gp1 = (4 + quad) ^ (lrow & 7);  // ks=1

    bf16x8  af[4][2];   // current m-half fragments
    bf16x8  bf[4][2];   // all 4 ni fragments
    floatx4 acc[8][4] = {};

    // prologue: stage t0 (8 loads) then t1 (8 loads); gate t0 with vmcnt(8)
    STAGE_T(0, 0);
    STAGE_T(1, 1);
    asm volatile("s_waitcnt vmcnt(8)" ::: "memory");
    __builtin_amdgcn_s_barrier();

#pragma unroll 1
    for (int i = 0; i < 8; ++i) {
        const int e = (2 * i + 2) & 15;   // wraps harmlessly on last iter (never read)
        const int o = (2 * i + 3) & 15;
        // ph1
        LOAD_A(0, 0); LOAD_B(0, 0);
        PH_OPEN(); MFMA_Q(0, 0); PH_CLOSE();
        // ph2
        LOAD_B(0, 1);
        PH_OPEN(); MFMA_Q(0, 1); PH_CLOSE();
        // ph3 — last reads of buf0
        LOAD_A(0, 1);
        PH_OPEN(); MFMA_Q(1, 0); PH_CLOSE();
        // ph4 — buf0 free: burst-stage t0+2; gate t1 (issued at prev ph8, 4 phases ago)
        STAGE_T(0, e);
        PH_OPEN(); MFMA_Q(1, 1); PH_CLOSE_VM8();
        // ph5
        LOAD_A(1, 0); LOAD_B(1, 0);
        PH_OPEN(); MFMA_Q(0, 0); PH_CLOSE();
        // ph6
        LOAD_B(1, 1);
        PH_OPEN(); MFMA_Q(0, 1); PH_CLOSE();
        // ph7 — last reads of buf1
        LOAD_A(1, 1);
        PH_OPEN(); MFMA_Q(1, 0); PH_CLOSE();
        // ph8 — buf1 free: burst-stage t1+2; gate t0+2 (issued at ph4, 4 phases ago)
        STAGE_T(1, o);
        PH_OPEN(); MFMA_Q(1, 1); PH_CLOSE_VM8();
    }
    asm volatile("s_waitcnt vmcnt(0)" ::: "memory");   // drain tail prefetches

    // epilogue: C[row][col] = acc + bias[col]
    const int crow0 = bm * BM + wm * 128 + quad * 4;
    const int ccol0 = bn * BN + wn * 64;
#pragma unroll
    for (int ni = 0; ni < 4; ++ni) {
        const int col = ccol0 + ni * 16 + lrow;
        const float bv = bias[col];
#pragma unroll
        for (int mi = 0; mi < 8; ++mi) {
            const int row = crow0 + mi * 16;
#pragma unroll
            for (int r = 0; r < 4; ++r)
                C[(size_t)(row + r) * N_OUT + col] = acc[mi][ni][r] + bv;
        }
    }
}

extern "C" void kernel_launch(void* const* d_in, const int* in_sizes, int n_in,
                              void* d_out, int out_size, void* d_ws, size_t ws_size,
                              hipStream_t stream) {
    const float* x    = (const float*)d_in[0];   // [32768,1024]
    const float* w    = (const float*)d_in[1];   // [1024,1024]
    const float* bias = (const float*)d_in[2];   // [1024]
    float* out        = (float*)d_out;           // [32768,1024]

    unsigned short* xb = (unsigned short*)d_ws;                                      // 64 MB
    unsigned short* wb = (unsigned short*)((char*)d_ws + (size_t)M_TOK * K_IN * 2);  // 2 MB

    static bool attr_set = false;
    if (!attr_set) {
        hipFuncSetAttribute((const void*)gemm8p,
                            hipFuncAttributeMaxDynamicSharedMemorySize, 131072);
        attr_set = true;
    }

    cvt_x_kernel<<<2048, 256, 0, stream>>>(x, xb);
    cvt_w_kernel<<<1024, 256, 0, stream>>>(w, wb);
    gemm8p<<<(M_TOK / BM) * (N_OUT / BN), 512, 131072, stream>>>(xb, wb, bias, out);
}